// Round 1
// baseline (244.034 us; speedup 1.0000x reference)
//
#include <hip/hip_runtime.h>

#define HT 64
#define WD 64
#define NN 4096           // HT*WD
#define CAP 1024          // LDS cache capacity per row (actual max nnz/row ~45)

// ---- Pass 1: per-row nnz histogram + row sums of Wcm (= cmw[r] * sum of data) ----
__global__ void k_hist(const int* __restrict__ row, const float* __restrict__ data,
                       const float* __restrict__ cmw, int nnz,
                       int* __restrict__ cnt, float* __restrict__ rowsum) {
    int e = blockIdx.x * blockDim.x + threadIdx.x;
    if (e >= nnz) return;
    int r = row[e];
    atomicAdd(&cnt[r], 1);
    atomicAdd(&rowsum[r], data[e] * cmw[r]);
}

// ---- Pass 2: exclusive scan of 4096 counts (single block, 256 threads x 16) ----
__global__ void k_scan(const int* __restrict__ cnt, int* __restrict__ off,
                       int* __restrict__ cur) {
    __shared__ int partial[256];
    __shared__ int pscan[257];
    int t = threadIdx.x;
    int base = t * 16;
    int local[16];
    int s = 0;
    for (int i = 0; i < 16; i++) { local[i] = cnt[base + i]; s += local[i]; }
    partial[t] = s;
    __syncthreads();
    if (t == 0) {
        int acc = 0;
        for (int i = 0; i < 256; i++) { pscan[i] = acc; acc += partial[i]; }
        pscan[256] = acc;
    }
    __syncthreads();
    int acc = pscan[t];
    for (int i = 0; i < 16; i++) {
        off[base + i] = acc;
        cur[base + i] = acc;
        acc += local[i];
    }
    if (t == 0) off[NN] = pscan[256];
}

// ---- Pass 3: counting-sort scatter; store Lcm off-diag value = -data*cmw[r] ----
__global__ void k_scatter(const int* __restrict__ row, const int* __restrict__ col,
                          const float* __restrict__ data, const float* __restrict__ cmw,
                          int nnz, int* __restrict__ cur,
                          int* __restrict__ scol, float* __restrict__ sval) {
    int e = blockIdx.x * blockDim.x + threadIdx.x;
    if (e >= nnz) return;
    int r = row[e];
    int pos = atomicAdd(&cur[r], 1);
    scol[pos] = col[e];
    sval[pos] = -data[e] * cmw[r];
}

// ---- Pass 4: per-row outer product: A[ci,cj] += vi*vj over all entry pairs ----
__global__ void k_outer(const int* __restrict__ off, const int* __restrict__ scol,
                        const float* __restrict__ sval, const float* __restrict__ rowsum,
                        float* __restrict__ A) {
    __shared__ int   lc[CAP];
    __shared__ float lv[CAP];
    int k = blockIdx.x;
    int base = off[k];
    int nnz_k = off[k + 1] - base;
    int total = nnz_k + 1;   // + synthetic diagonal entry (k, rowsum[k])
    for (int i = threadIdx.x; i < total && i < CAP; i += blockDim.x) {
        if (i < nnz_k) { lc[i] = scol[base + i]; lv[i] = sval[base + i]; }
        else           { lc[i] = k;              lv[i] = rowsum[k]; }
    }
    __syncthreads();
    long long np = (long long)total * (long long)total;
    for (long long p = threadIdx.x; p < np; p += blockDim.x) {
        int i = (int)(p / total);
        int j = (int)(p % total);
        int ci, cj; float vi, vj;
        if (i < CAP) { ci = lc[i]; vi = lv[i]; }
        else if (i < nnz_k) { ci = scol[base + i]; vi = sval[base + i]; }
        else { ci = k; vi = rowsum[k]; }
        if (j < CAP) { cj = lc[j]; vj = lv[j]; }
        else if (j < nnz_k) { cj = scol[base + j]; vj = sval[base + j]; }
        else { cj = k; vj = rowsum[k]; }
        atomicAdd(&A[ci * NN + cj], vi * vj);
    }
}

// ---- LOC symmetric Laplacian scatter ----
__global__ void k_loc(const int* __restrict__ inInd, const float* __restrict__ flows,
                      const float* __restrict__ locw, int M, float* __restrict__ A) {
    int t = blockIdx.x * blockDim.x + threadIdx.x;
    if (t >= M * 9) return;
    int m = t / 9, j = t % 9;
    const int offs[9] = {-1 - WD, -1, -1 + WD, -WD, 0, WD, 1 - WD, 1, 1 + WD};
    int ind = inInd[m];
    int r = ind - 1 - WD;             // neigh[m,0]
    int c = ind + offs[j];
    float v = flows[j * 9 * M + m] * locw[ind];   // LOC_flows[j,0,m] * w_loc
    float h = 0.5f * v;
    atomicAdd(&A[r * NN + c], -h);
    atomicAdd(&A[c * NN + r], -h);
    atomicAdd(&A[r * NN + r],  h);
    atomicAdd(&A[c * NN + c],  h);
}

// ---- IU symmetric Laplacian scatter ----
__global__ void k_iu(const int* __restrict__ inInd, const float* __restrict__ flows,
                     const int* __restrict__ neigh, const float* __restrict__ iuw,
                     int M, float* __restrict__ A) {
    int t = blockIdx.x * blockDim.x + threadIdx.x;
    if (t >= M * 5) return;
    int m = t / 5, j = t % 5;
    int r = inInd[m];
    int c = neigh[m * 5 + j];
    float v = flows[m * 5 + j] * iuw[r];
    float h = 0.5f * v;
    atomicAdd(&A[r * NN + c], -h);
    atomicAdd(&A[c * NN + r], -h);
    atomicAdd(&A[r * NN + r],  h);
    atomicAdd(&A[c * NN + c],  h);
}

// ---- Final diagonal + b ----
__global__ void k_diag(const float* __restrict__ kuw, const float* __restrict__ conf,
                       const float* __restrict__ known, const float* __restrict__ kToU,
                       const float* __restrict__ lmbda,
                       float* __restrict__ A, float* __restrict__ b) {
    int i = blockIdx.x * blockDim.x + threadIdx.x;
    if (i >= NN) return;
    float d = kuw[i] * conf[i] + lmbda[0] * known[i];
    atomicAdd(&A[i * NN + i], d);
    b[i] = d * kToU[i];
}

extern "C" void kernel_launch(void* const* d_in, const int* in_sizes, int n_in,
                              void* d_out, int out_size, void* d_ws, size_t ws_size,
                              hipStream_t stream) {
    const float* CM_weights  = (const float*)d_in[2];
    const float* LOC_weights = (const float*)d_in[3];
    const float* IU_weights  = (const float*)d_in[4];
    const float* KU_weights  = (const float*)d_in[5];
    const float* lmbda       = (const float*)d_in[6];
    const float* kToUconf    = (const float*)d_in[7];
    const float* known       = (const float*)d_in[8];
    const float* kToU        = (const float*)d_in[9];
    const int*   Wcm_row     = (const int*)d_in[10];
    const int*   Wcm_col     = (const int*)d_in[11];
    const float* Wcm_data    = (const float*)d_in[12];
    const int*   LOC_inInd   = (const int*)d_in[13];
    const float* LOC_flows   = (const float*)d_in[14];
    const int*   IU_inInd    = (const int*)d_in[15];
    const float* IU_flows    = (const float*)d_in[16];
    const int*   IU_neighInd = (const int*)d_in[17];

    int nnz  = in_sizes[10];
    int mloc = in_sizes[13];
    int miu  = in_sizes[15];

    float* A = (float*)d_out;
    float* b = A + (size_t)NN * NN;

    // workspace layout: cnt[NN] | off[NN+1] | cur[NN] | rowsum[NN] | scol[nnz] | sval[nnz]
    int*   cnt    = (int*)d_ws;
    int*   off    = cnt + NN;
    int*   cur    = off + NN + 1;
    float* rowsum = (float*)(cur + NN);
    int*   scol   = (int*)(rowsum + NN);
    float* sval   = (float*)(scol + nnz);

    hipMemsetAsync(d_out, 0, (size_t)out_size * sizeof(float), stream);
    hipMemsetAsync(cnt, 0, NN * sizeof(int), stream);
    hipMemsetAsync(rowsum, 0, NN * sizeof(float), stream);

    k_hist<<<(nnz + 255) / 256, 256, 0, stream>>>(Wcm_row, Wcm_data, CM_weights, nnz, cnt, rowsum);
    k_scan<<<1, 256, 0, stream>>>(cnt, off, cur);
    k_scatter<<<(nnz + 255) / 256, 256, 0, stream>>>(Wcm_row, Wcm_col, Wcm_data, CM_weights,
                                                     nnz, cur, scol, sval);
    k_outer<<<NN, 256, 0, stream>>>(off, scol, sval, rowsum, A);
    k_loc<<<(mloc * 9 + 255) / 256, 256, 0, stream>>>(LOC_inInd, LOC_flows, LOC_weights, mloc, A);
    k_iu<<<(miu * 5 + 255) / 256, 256, 0, stream>>>(IU_inInd, IU_flows, IU_neighInd, IU_weights, miu, A);
    k_diag<<<(NN + 255) / 256, 256, 0, stream>>>(KU_weights, kToUconf, known, kToU, lmbda, A, b);
}

// Round 2
// 160.002 us; speedup vs baseline: 1.5252x; 1.5252x over previous
//
#include <hip/hip_runtime.h>

#define WD 64
#define NN 4096
#define COLCAP 96   // max CSC entries cached in LDS; Poisson(20) tail >> covered, overflow path exists

// ---- Pass 1: histograms (CSR rows, CSC cols, extras rows) + Lcm row sums ----
__global__ void k_hist_all(const int* __restrict__ wrow, const int* __restrict__ wcol,
                           const float* __restrict__ wdata, const float* __restrict__ cmw,
                           const int* __restrict__ locInd,
                           const int* __restrict__ iuInd, const int* __restrict__ iuNeigh,
                           int nnz, int mloc, int miu,
                           int* __restrict__ cntR, int* __restrict__ cntC,
                           int* __restrict__ cntX, float* __restrict__ rowsum) {
    int t = blockIdx.x * blockDim.x + threadIdx.x;
    if (t < nnz) {
        int r = wrow[t], c = wcol[t];
        atomicAdd(&cntR[r], 1);
        atomicAdd(&cntC[c], 1);
        atomicAdd(&rowsum[r], wdata[t] * cmw[r]);
        return;
    }
    t -= nnz;
    if (t < mloc * 9) {
        int m = t / 9;
        int j = t - m * 9;
        const int offs[9] = {-1-WD, -1, -1+WD, -WD, 0, WD, 1-WD, 1, 1+WD};
        int ind = locInd[m];
        int r = ind - 1 - WD;
        int c = ind + offs[j];
        atomicAdd(&cntX[r], 2);
        atomicAdd(&cntX[c], 2);
        return;
    }
    t -= mloc * 9;
    if (t < miu * 5) {
        int m = t / 5;
        int j = t - m * 5;
        int r = iuInd[m];
        int c = iuNeigh[m * 5 + j];
        atomicAdd(&cntX[r], 2);
        atomicAdd(&cntX[c], 2);
    }
}

// ---- Pass 2: three independent exclusive scans (grid = 3 blocks) ----
__global__ void k_scan3(const int* __restrict__ cntBase, int* __restrict__ offBase,
                        int* __restrict__ curBase) {
    const int* cnt = cntBase + blockIdx.x * NN;
    int* off = offBase + blockIdx.x * (NN + 1);
    int* cur = curBase + blockIdx.x * NN;
    __shared__ int partial[256];
    __shared__ int pscan[257];
    int tdx = threadIdx.x;
    int base = tdx * 16;
    int local[16];
    int s = 0;
    for (int i = 0; i < 16; i++) { local[i] = cnt[base + i]; s += local[i]; }
    partial[tdx] = s;
    __syncthreads();
    if (tdx == 0) {
        int a = 0;
        for (int i = 0; i < 256; i++) { pscan[i] = a; a += partial[i]; }
        pscan[256] = a;
    }
    __syncthreads();
    int a = pscan[tdx];
    for (int i = 0; i < 16; i++) { off[base + i] = a; cur[base + i] = a; a += local[i]; }
    if (tdx == 0) off[NN] = pscan[256];
}

// ---- Pass 3: counting-sort scatter: CSR(Lcm offdiag), CSC(Lcm offdiag), extras ----
__global__ void k_scatter_all(const int* __restrict__ wrow, const int* __restrict__ wcol,
                              const float* __restrict__ wdata, const float* __restrict__ cmw,
                              const int* __restrict__ locInd, const float* __restrict__ locFlows,
                              const float* __restrict__ locw,
                              const int* __restrict__ iuInd, const float* __restrict__ iuFlows,
                              const int* __restrict__ iuNeigh, const float* __restrict__ iuw,
                              int nnz, int mloc, int miu,
                              int* __restrict__ curR, int* __restrict__ curC, int* __restrict__ curX,
                              int* __restrict__ scolR, float* __restrict__ svalR,
                              int* __restrict__ srowC, float* __restrict__ svalC,
                              int* __restrict__ xcol, float* __restrict__ xval) {
    int t = blockIdx.x * blockDim.x + threadIdx.x;
    if (t < nnz) {
        int r = wrow[t], c = wcol[t];
        float v = -wdata[t] * cmw[r];         // Lcm off-diagonal value
        int pR = atomicAdd(&curR[r], 1);
        scolR[pR] = c; svalR[pR] = v;
        int pC = atomicAdd(&curC[c], 1);
        srowC[pC] = r; svalC[pC] = v;
        return;
    }
    t -= nnz;
    if (t < mloc * 9) {
        int m = t / 9;
        int j = t - m * 9;
        const int offs[9] = {-1-WD, -1, -1+WD, -WD, 0, WD, 1-WD, 1, 1+WD};
        int ind = locInd[m];
        int r = ind - 1 - WD;
        int c = ind + offs[j];
        float h = 0.5f * locFlows[j * 9 * mloc + m] * locw[ind];
        int p1 = atomicAdd(&curX[r], 2);
        xcol[p1] = c;     xval[p1] = -h;      // A[r,c] -= h
        xcol[p1 + 1] = r; xval[p1 + 1] = h;   // A[r,r] += h
        int p2 = atomicAdd(&curX[c], 2);
        xcol[p2] = r;     xval[p2] = -h;      // A[c,r] -= h
        xcol[p2 + 1] = c; xval[p2 + 1] = h;   // A[c,c] += h
        return;
    }
    t -= mloc * 9;
    if (t < miu * 5) {
        int m = t / 5;
        int j = t - m * 5;
        int r = iuInd[m];
        int c = iuNeigh[m * 5 + j];
        float h = 0.5f * iuFlows[m * 5 + j] * iuw[r];
        int p1 = atomicAdd(&curX[r], 2);
        xcol[p1] = c;     xval[p1] = -h;
        xcol[p1 + 1] = r; xval[p1 + 1] = h;
        int p2 = atomicAdd(&curX[c], 2);
        xcol[p2] = r;     xval[p2] = -h;
        xcol[p2 + 1] = c; xval[p2 + 1] = h;
    }
}

// ---- Pass 4: one block per output row; dense LDS accumulator; single streaming write ----
__global__ void __launch_bounds__(256) k_rows(
    const int* __restrict__ offR, const int* __restrict__ scolR, const float* __restrict__ svalR,
    const int* __restrict__ offC, const int* __restrict__ srowC, const float* __restrict__ svalC,
    const int* __restrict__ offX, const int* __restrict__ xcol, const float* __restrict__ xval,
    const float* __restrict__ rowsum,
    const float* __restrict__ kuw, const float* __restrict__ conf, const float* __restrict__ known,
    const float* __restrict__ kToU, const float* __restrict__ lmbda,
    float* __restrict__ A, float* __restrict__ b) {
    __shared__ float acc[NN];
    __shared__ int   ck[COLCAP];
    __shared__ float cv[COLCAP];
    int i = blockIdx.x;
    int tid = threadIdx.x;

    float4* acc4 = (float4*)acc;
    for (int t = tid; t < NN / 4; t += 256) acc4[t] = make_float4(0.f, 0.f, 0.f, 0.f);

    int cbase = offC[i];
    int ccnt = offC[i + 1] - cbase;
    int ctot = ccnt + 1;                      // + synthetic diagonal entry (i, rowsum[i])
    for (int t = tid; t < ctot; t += 256) {
        if (t >= COLCAP) continue;
        if (t < ccnt) { ck[t] = srowC[cbase + t]; cv[t] = svalC[cbase + t]; }
        else          { ck[t] = i;               cv[t] = rowsum[i]; }
    }
    __syncthreads();

    int wave = tid >> 6, lane = tid & 63;
    // A[i,j] = sum over column-i entries (k,v) of v * Lcm[k,j]
    for (int kk = wave; kk < ctot; kk += 4) {
        int k; float v;
        if (kk < COLCAP)    { k = ck[kk]; v = cv[kk]; }
        else if (kk < ccnt) { k = srowC[cbase + kk]; v = svalC[cbase + kk]; }
        else                { k = i; v = rowsum[i]; }
        int rb = offR[k];
        int rl = offR[k + 1] - rb;
        for (int t = lane; t <= rl; t += 64) { // rl entries + 1 synthetic diag (k, rowsum[k])
            int j; float w;
            if (t < rl) { j = scolR[rb + t]; w = svalR[rb + t]; }
            else        { j = k; w = rowsum[k]; }
            atomicAdd(&acc[j], v * w);
        }
    }
    // LOC/IU grouped contributions for this row
    for (int t = offX[i] + tid; t < offX[i + 1]; t += 256) {
        atomicAdd(&acc[xcol[t]], xval[t]);
    }
    // diagonal regularizer + b
    if (tid == 0) {
        float d = kuw[i] * conf[i] + lmbda[0] * known[i];
        atomicAdd(&acc[i], d);
        b[i] = d * kToU[i];
    }
    __syncthreads();

    float4* out4 = (float4*)(A + (size_t)i * NN);
    for (int t = tid; t < NN / 4; t += 256) out4[t] = acc4[t];
}

extern "C" void kernel_launch(void* const* d_in, const int* in_sizes, int n_in,
                              void* d_out, int out_size, void* d_ws, size_t ws_size,
                              hipStream_t stream) {
    const float* CM_weights  = (const float*)d_in[2];
    const float* LOC_weights = (const float*)d_in[3];
    const float* IU_weights  = (const float*)d_in[4];
    const float* KU_weights  = (const float*)d_in[5];
    const float* lmbda       = (const float*)d_in[6];
    const float* kToUconf    = (const float*)d_in[7];
    const float* known       = (const float*)d_in[8];
    const float* kToU        = (const float*)d_in[9];
    const int*   Wcm_row     = (const int*)d_in[10];
    const int*   Wcm_col     = (const int*)d_in[11];
    const float* Wcm_data    = (const float*)d_in[12];
    const int*   LOC_inInd   = (const int*)d_in[13];
    const float* LOC_flows   = (const float*)d_in[14];
    const int*   IU_inInd    = (const int*)d_in[15];
    const float* IU_flows    = (const float*)d_in[16];
    const int*   IU_neighInd = (const int*)d_in[17];

    int nnz  = in_sizes[10];
    int mloc = in_sizes[13];
    int miu  = in_sizes[15];
    int xtot = 4 * (mloc * 9 + miu * 5);

    float* A = (float*)d_out;
    float* b = A + (size_t)NN * NN;

    // workspace layout (4B words):
    // [cntR|cntC|cntX|rowsum] (zeroed) | offR|offC|offX (4097 ea) | curR|curC|curX |
    // scolR|svalR (nnz ea) | srowC|svalC (nnz ea) | xcol|xval (xtot ea)
    int*   cntR   = (int*)d_ws;
    int*   cntC   = cntR + NN;
    int*   cntX   = cntC + NN;
    float* rowsum = (float*)(cntX + NN);
    int*   offR   = (int*)(rowsum + NN);   // stride NN+1 for the 3 arrays
    int*   offC   = offR + (NN + 1);
    int*   offX   = offC + (NN + 1);
    int*   curR   = offX + (NN + 1);       // stride NN
    int*   curC   = curR + NN;
    int*   curX   = curC + NN;
    int*   scolR  = curX + NN;
    float* svalR  = (float*)(scolR + nnz);
    int*   srowC  = (int*)(svalR + nnz);
    float* svalC  = (float*)(srowC + nnz);
    int*   xcol   = (int*)(svalC + nnz);
    float* xval   = (float*)(xcol + xtot);

    hipMemsetAsync(cntR, 0, 4 * NN * sizeof(int), stream);  // cntR,cntC,cntX,rowsum

    int tt = nnz + mloc * 9 + miu * 5;
    int blks = (tt + 255) / 256;
    k_hist_all<<<blks, 256, 0, stream>>>(Wcm_row, Wcm_col, Wcm_data, CM_weights,
                                         LOC_inInd, IU_inInd, IU_neighInd,
                                         nnz, mloc, miu, cntR, cntC, cntX, rowsum);
    k_scan3<<<3, 256, 0, stream>>>(cntR, offR, curR);
    k_scatter_all<<<blks, 256, 0, stream>>>(Wcm_row, Wcm_col, Wcm_data, CM_weights,
                                            LOC_inInd, LOC_flows, LOC_weights,
                                            IU_inInd, IU_flows, IU_neighInd, IU_weights,
                                            nnz, mloc, miu, curR, curC, curX,
                                            scolR, svalR, srowC, svalC, xcol, xval);
    k_rows<<<NN, 256, 0, stream>>>(offR, scolR, svalR, offC, srowC, svalC,
                                   offX, xcol, xval, rowsum,
                                   KU_weights, kToUconf, known, kToU, lmbda, A, b);
}

// Round 3
// 142.685 us; speedup vs baseline: 1.7103x; 1.1214x over previous
//
#include <hip/hip_runtime.h>

#define WD 64
#define NN 4096
#define RCAP 128    // per-row bucket capacity, CSR and CSC of Lcm (max observed ~45, Poisson(20))
#define XCAP 512    // per-row bucket capacity, LOC/IU extras (avg ~28)

// ---- Pass 1: direct bucket scatter (CSR, CSC, extras) + Lcm row sums ----
__global__ void k_scatter(const int* __restrict__ wrow, const int* __restrict__ wcol,
                          const float* __restrict__ wdata, const float* __restrict__ cmw,
                          const int* __restrict__ locInd, const float* __restrict__ locFlows,
                          const float* __restrict__ locw,
                          const int* __restrict__ iuInd, const float* __restrict__ iuFlows,
                          const int* __restrict__ iuNeigh, const float* __restrict__ iuw,
                          int nnz, int mloc, int miu,
                          int* __restrict__ curR, int* __restrict__ curC, int* __restrict__ curX,
                          float* __restrict__ rowsum,
                          int* __restrict__ scolR, float* __restrict__ svalR,
                          int* __restrict__ srowC, float* __restrict__ svalC,
                          int* __restrict__ xcol, float* __restrict__ xval) {
    int t = blockIdx.x * blockDim.x + threadIdx.x;
    if (t < nnz) {
        int r = wrow[t], c = wcol[t];
        float v = -wdata[t] * cmw[r];          // Lcm off-diagonal value
        atomicAdd(&rowsum[r], wdata[t] * cmw[r]);
        int pR = atomicAdd(&curR[r], 1);
        if (pR < RCAP) { scolR[r * RCAP + pR] = c; svalR[r * RCAP + pR] = v; }
        int pC = atomicAdd(&curC[c], 1);
        if (pC < RCAP) { srowC[c * RCAP + pC] = r; svalC[c * RCAP + pC] = v; }
        return;
    }
    t -= nnz;
    if (t < mloc * 9) {
        int m = t / 9;
        int j = t - m * 9;
        const int offs[9] = {-1-WD, -1, -1+WD, -WD, 0, WD, 1-WD, 1, 1+WD};
        int ind = locInd[m];
        int r = ind - 1 - WD;                  // neigh[m,0]
        int c = ind + offs[j];
        float h = 0.5f * locFlows[j * 9 * mloc + m] * locw[ind];
        int p1 = atomicAdd(&curX[r], 2);
        if (p1 + 1 < XCAP) {
            xcol[r * XCAP + p1] = c;     xval[r * XCAP + p1] = -h;   // A[r,c] -= h
            xcol[r * XCAP + p1 + 1] = r; xval[r * XCAP + p1 + 1] = h; // A[r,r] += h
        }
        int p2 = atomicAdd(&curX[c], 2);
        if (p2 + 1 < XCAP) {
            xcol[c * XCAP + p2] = r;     xval[c * XCAP + p2] = -h;   // A[c,r] -= h
            xcol[c * XCAP + p2 + 1] = c; xval[c * XCAP + p2 + 1] = h; // A[c,c] += h
        }
        return;
    }
    t -= mloc * 9;
    if (t < miu * 5) {
        int m = t / 5;
        int j = t - m * 5;
        int r = iuInd[m];
        int c = iuNeigh[m * 5 + j];
        float h = 0.5f * iuFlows[m * 5 + j] * iuw[r];
        int p1 = atomicAdd(&curX[r], 2);
        if (p1 + 1 < XCAP) {
            xcol[r * XCAP + p1] = c;     xval[r * XCAP + p1] = -h;
            xcol[r * XCAP + p1 + 1] = r; xval[r * XCAP + p1 + 1] = h;
        }
        int p2 = atomicAdd(&curX[c], 2);
        if (p2 + 1 < XCAP) {
            xcol[c * XCAP + p2] = r;     xval[c * XCAP + p2] = -h;
            xcol[c * XCAP + p2 + 1] = c; xval[c * XCAP + p2 + 1] = h;
        }
    }
}

// ---- Pass 2: one block per output row; dense LDS accumulator; single streaming write ----
__global__ void __launch_bounds__(256) k_rows(
    const int* __restrict__ curR, const int* __restrict__ scolR, const float* __restrict__ svalR,
    const int* __restrict__ curC, const int* __restrict__ srowC, const float* __restrict__ svalC,
    const int* __restrict__ curX, const int* __restrict__ xcol, const float* __restrict__ xval,
    const float* __restrict__ rowsum,
    const float* __restrict__ kuw, const float* __restrict__ conf, const float* __restrict__ known,
    const float* __restrict__ kToU, const float* __restrict__ lmbda,
    float* __restrict__ A, float* __restrict__ b) {
    __shared__ float acc[NN];
    __shared__ int   ck[RCAP + 1];
    __shared__ float cv[RCAP + 1];
    int i = blockIdx.x;
    int tid = threadIdx.x;

    float4* acc4 = (float4*)acc;
    for (int t = tid; t < NN / 4; t += 256) acc4[t] = make_float4(0.f, 0.f, 0.f, 0.f);

    int ccnt = min(curC[i], RCAP);
    int ctot = ccnt + 1;                       // + synthetic diagonal entry (i, rowsum[i])
    for (int t = tid; t < ctot; t += 256) {
        if (t < ccnt) { ck[t] = srowC[i * RCAP + t]; cv[t] = svalC[i * RCAP + t]; }
        else          { ck[t] = i;                   cv[t] = rowsum[i]; }
    }
    __syncthreads();

    int wave = tid >> 6, lane = tid & 63;
    // A[i,j] = sum over column-i entries (k,v) of v * Lcm[k,j]
    for (int kk = wave; kk < ctot; kk += 4) {
        int k = ck[kk];
        float v = cv[kk];
        int rl = min(curR[k], RCAP);
        int rb = k * RCAP;
        for (int t = lane; t <= rl; t += 64) { // rl entries + synthetic diag (k, rowsum[k])
            int j; float w;
            if (t < rl) { j = scolR[rb + t]; w = svalR[rb + t]; }
            else        { j = k; w = rowsum[k]; }
            atomicAdd(&acc[j], v * w);
        }
    }
    // LOC/IU grouped contributions for this row
    int xc = min(curX[i], XCAP);
    for (int t = tid; t < xc; t += 256) {
        atomicAdd(&acc[xcol[i * XCAP + t]], xval[i * XCAP + t]);
    }
    // diagonal regularizer + b
    if (tid == 0) {
        float d = kuw[i] * conf[i] + lmbda[0] * known[i];
        atomicAdd(&acc[i], d);
        b[i] = d * kToU[i];
    }
    __syncthreads();

    float4* out4 = (float4*)(A + (size_t)i * NN);
    for (int t = tid; t < NN / 4; t += 256) out4[t] = acc4[t];
}

extern "C" void kernel_launch(void* const* d_in, const int* in_sizes, int n_in,
                              void* d_out, int out_size, void* d_ws, size_t ws_size,
                              hipStream_t stream) {
    const float* CM_weights  = (const float*)d_in[2];
    const float* LOC_weights = (const float*)d_in[3];
    const float* IU_weights  = (const float*)d_in[4];
    const float* KU_weights  = (const float*)d_in[5];
    const float* lmbda       = (const float*)d_in[6];
    const float* kToUconf    = (const float*)d_in[7];
    const float* known       = (const float*)d_in[8];
    const float* kToU        = (const float*)d_in[9];
    const int*   Wcm_row     = (const int*)d_in[10];
    const int*   Wcm_col     = (const int*)d_in[11];
    const float* Wcm_data    = (const float*)d_in[12];
    const int*   LOC_inInd   = (const int*)d_in[13];
    const float* LOC_flows   = (const float*)d_in[14];
    const int*   IU_inInd    = (const int*)d_in[15];
    const float* IU_flows    = (const float*)d_in[16];
    const int*   IU_neighInd = (const int*)d_in[17];

    int nnz  = in_sizes[10];
    int mloc = in_sizes[13];
    int miu  = in_sizes[15];

    float* A = (float*)d_out;
    float* b = A + (size_t)NN * NN;

    // workspace layout (4B words):
    // [curR|curC|curX|rowsum] (zeroed, 4*NN) |
    // scolR|svalR (NN*RCAP ea) | srowC|svalC (NN*RCAP ea) | xcol|xval (NN*XCAP ea)
    int*   curR   = (int*)d_ws;
    int*   curC   = curR + NN;
    int*   curX   = curC + NN;
    float* rowsum = (float*)(curX + NN);
    int*   scolR  = (int*)(rowsum + NN);
    float* svalR  = (float*)(scolR + NN * RCAP);
    int*   srowC  = (int*)(svalR + NN * RCAP);
    float* svalC  = (float*)(srowC + NN * RCAP);
    int*   xcol   = (int*)(svalC + NN * RCAP);
    float* xval   = (float*)(xcol + NN * XCAP);

    hipMemsetAsync(curR, 0, 4 * NN * sizeof(int), stream);  // curR,curC,curX,rowsum

    int tt = nnz + mloc * 9 + miu * 5;
    int blks = (tt + 255) / 256;
    k_scatter<<<blks, 256, 0, stream>>>(Wcm_row, Wcm_col, Wcm_data, CM_weights,
                                        LOC_inInd, LOC_flows, LOC_weights,
                                        IU_inInd, IU_flows, IU_neighInd, IU_weights,
                                        nnz, mloc, miu, curR, curC, curX, rowsum,
                                        scolR, svalR, srowC, svalC, xcol, xval);
    k_rows<<<NN, 256, 0, stream>>>(curR, scolR, svalR, curC, srowC, svalC,
                                   curX, xcol, xval, rowsum,
                                   KU_weights, kToUconf, known, kToU, lmbda, A, b);
}

// Round 5
// 137.981 us; speedup vs baseline: 1.7686x; 1.0341x over previous
//
#include <hip/hip_runtime.h>

#define WD 64
#define NN 4096
#define RCAP 128    // per-row bucket capacity, CSR and CSC of Lcm (max observed ~45, Poisson(20))
#define XCAP 512    // per-row bucket capacity, LOC/IU extras (avg ~28)

typedef float v4f __attribute__((ext_vector_type(4)));  // native vector: nontemporal-store OK

// Buckets hold packed entries: int2{ index, float_bits(value) }

// ---- Pass 1: direct bucket scatter (CSR, CSC, extras) + Lcm row sums ----
__global__ void k_scatter(const int* __restrict__ wrow, const int* __restrict__ wcol,
                          const float* __restrict__ wdata, const float* __restrict__ cmw,
                          const int* __restrict__ locInd, const float* __restrict__ locFlows,
                          const float* __restrict__ locw,
                          const int* __restrict__ iuInd, const float* __restrict__ iuFlows,
                          const int* __restrict__ iuNeigh, const float* __restrict__ iuw,
                          int nnz, int mloc, int miu,
                          int* __restrict__ curR, int* __restrict__ curC, int* __restrict__ curX,
                          float* __restrict__ rowsum,
                          int2* __restrict__ sR, int2* __restrict__ sC, int2* __restrict__ xE) {
    int t = blockIdx.x * blockDim.x + threadIdx.x;
    if (t < nnz) {
        int r = wrow[t], c = wcol[t];
        float pos = wdata[t] * cmw[r];
        float v = -pos;                        // Lcm off-diagonal value
        atomicAdd(&rowsum[r], pos);
        int pR = atomicAdd(&curR[r], 1);
        if (pR < RCAP) sR[r * RCAP + pR] = make_int2(c, __float_as_int(v));
        int pC = atomicAdd(&curC[c], 1);
        if (pC < RCAP) sC[c * RCAP + pC] = make_int2(r, __float_as_int(v));
        return;
    }
    t -= nnz;
    if (t < mloc * 9) {
        int m = t / 9;
        int j = t - m * 9;
        const int offs[9] = {-1-WD, -1, -1+WD, -WD, 0, WD, 1-WD, 1, 1+WD};
        int ind = locInd[m];
        int r = ind - 1 - WD;                  // neigh[m,0]
        int c = ind + offs[j];
        float h = 0.5f * locFlows[j * 9 * mloc + m] * locw[ind];
        int p1 = atomicAdd(&curX[r], 2);
        if (p1 + 1 < XCAP) {
            xE[r * XCAP + p1]     = make_int2(c, __float_as_int(-h)); // A[r,c] -= h
            xE[r * XCAP + p1 + 1] = make_int2(r, __float_as_int( h)); // A[r,r] += h
        }
        int p2 = atomicAdd(&curX[c], 2);
        if (p2 + 1 < XCAP) {
            xE[c * XCAP + p2]     = make_int2(r, __float_as_int(-h)); // A[c,r] -= h
            xE[c * XCAP + p2 + 1] = make_int2(c, __float_as_int( h)); // A[c,c] += h
        }
        return;
    }
    t -= mloc * 9;
    if (t < miu * 5) {
        int m = t / 5;
        int j = t - m * 5;
        int r = iuInd[m];
        int c = iuNeigh[m * 5 + j];
        float h = 0.5f * iuFlows[m * 5 + j] * iuw[r];
        int p1 = atomicAdd(&curX[r], 2);
        if (p1 + 1 < XCAP) {
            xE[r * XCAP + p1]     = make_int2(c, __float_as_int(-h));
            xE[r * XCAP + p1 + 1] = make_int2(r, __float_as_int( h));
        }
        int p2 = atomicAdd(&curX[c], 2);
        if (p2 + 1 < XCAP) {
            xE[c * XCAP + p2]     = make_int2(r, __float_as_int(-h));
            xE[c * XCAP + p2 + 1] = make_int2(c, __float_as_int( h));
        }
    }
}

// ---- Pass 2: one block per output row; dense LDS accumulator; single streaming write ----
__global__ void __launch_bounds__(256) k_rows(
    const int* __restrict__ curR, const int2* __restrict__ sR,
    const int* __restrict__ curC, const int2* __restrict__ sC,
    const int* __restrict__ curX, const int2* __restrict__ xE,
    const float* __restrict__ rowsum,
    const float* __restrict__ kuw, const float* __restrict__ conf, const float* __restrict__ known,
    const float* __restrict__ kToU, const float* __restrict__ lmbda,
    float* __restrict__ A, float* __restrict__ b) {
    __shared__ float acc[NN];
    __shared__ int   ck[RCAP + 1];   // CSC row index k
    __shared__ float cv[RCAP + 1];   // Lcm[k,i]
    __shared__ int   crl[RCAP + 1];  // nnz of CSR row k
    __shared__ float crs[RCAP + 1];  // rowsum[k] (synthetic diagonal of row k)
    int i = blockIdx.x;
    int tid = threadIdx.x;

    v4f* acc4 = (v4f*)acc;
    for (int t = tid; t < NN / 4; t += 256) acc4[t] = (v4f){0.f, 0.f, 0.f, 0.f};

    int ccnt = min(curC[i], RCAP);
    int ctot = ccnt + 1;                       // + synthetic diagonal entry (i, rowsum[i])
    for (int t = tid; t < ctot; t += 256) {
        int k; float v;
        if (t < ccnt) { int2 e = sC[i * RCAP + t]; k = e.x; v = __int_as_float(e.y); }
        else          { k = i;                     v = rowsum[i]; }
        ck[t] = k; cv[t] = v;
        crl[t] = min(curR[k], RCAP);
        crs[t] = rowsum[k];
    }
    __syncthreads();

    // A[i,j] = sum over column-i entries (k,v) of v * Lcm[k,j]
    // two k per wave (half-wave each) for ~2x lane utilization at ~22 nnz/row
    int wave = tid >> 6, lane = tid & 63;
    int sub = lane >> 5, hl = lane & 31;
    for (int kk = wave * 2 + sub; kk < ctot; kk += 8) {
        int k = ck[kk];
        float v = cv[kk];
        int rl = crl[kk];
        const int2* rowp = sR + k * RCAP;
        for (int t = hl; t <= rl; t += 32) {   // rl entries + synthetic diag (k, rowsum[k])
            int j; float w;
            if (t < rl) { int2 e = rowp[t]; j = e.x; w = __int_as_float(e.y); }
            else        { j = k; w = crs[kk]; }
            atomicAdd(&acc[j], v * w);
        }
    }
    // LOC/IU grouped contributions for this row
    int xc = min(curX[i], XCAP);
    const int2* xp = xE + i * XCAP;
    for (int t = tid; t < xc; t += 256) {
        int2 e = xp[t];
        atomicAdd(&acc[e.x], __int_as_float(e.y));
    }
    // diagonal regularizer + b
    if (tid == 0) {
        float d = kuw[i] * conf[i] + lmbda[0] * known[i];
        atomicAdd(&acc[i], d);
        b[i] = d * kToU[i];
    }
    __syncthreads();

    v4f* out4 = (v4f*)(A + (size_t)i * NN);
    for (int t = tid; t < NN / 4; t += 256)
        __builtin_nontemporal_store(acc4[t], &out4[t]);  // A > L2 capacity; don't pollute
}

extern "C" void kernel_launch(void* const* d_in, const int* in_sizes, int n_in,
                              void* d_out, int out_size, void* d_ws, size_t ws_size,
                              hipStream_t stream) {
    const float* CM_weights  = (const float*)d_in[2];
    const float* LOC_weights = (const float*)d_in[3];
    const float* IU_weights  = (const float*)d_in[4];
    const float* KU_weights  = (const float*)d_in[5];
    const float* lmbda       = (const float*)d_in[6];
    const float* kToUconf    = (const float*)d_in[7];
    const float* known       = (const float*)d_in[8];
    const float* kToU        = (const float*)d_in[9];
    const int*   Wcm_row     = (const int*)d_in[10];
    const int*   Wcm_col     = (const int*)d_in[11];
    const float* Wcm_data    = (const float*)d_in[12];
    const int*   LOC_inInd   = (const int*)d_in[13];
    const float* LOC_flows   = (const float*)d_in[14];
    const int*   IU_inInd    = (const int*)d_in[15];
    const float* IU_flows    = (const float*)d_in[16];
    const int*   IU_neighInd = (const int*)d_in[17];

    int nnz  = in_sizes[10];
    int mloc = in_sizes[13];
    int miu  = in_sizes[15];

    float* A = (float*)d_out;
    float* b = A + (size_t)NN * NN;

    // workspace layout (4B words):
    // [curR|curC|curX|rowsum] (zeroed, 4*NN) |
    // sR (NN*RCAP int2) | sC (NN*RCAP int2) | xE (NN*XCAP int2)   ~24 MB total
    int*   curR   = (int*)d_ws;
    int*   curC   = curR + NN;
    int*   curX   = curC + NN;
    float* rowsum = (float*)(curX + NN);
    int2*  sR     = (int2*)(rowsum + NN);
    int2*  sC     = sR + (size_t)NN * RCAP;
    int2*  xE     = sC + (size_t)NN * RCAP;

    (void)hipMemsetAsync(curR, 0, 4 * NN * sizeof(int), stream);  // curR,curC,curX,rowsum

    int tt = nnz + mloc * 9 + miu * 5;
    int blks = (tt + 255) / 256;
    k_scatter<<<blks, 256, 0, stream>>>(Wcm_row, Wcm_col, Wcm_data, CM_weights,
                                        LOC_inInd, LOC_flows, LOC_weights,
                                        IU_inInd, IU_flows, IU_neighInd, IU_weights,
                                        nnz, mloc, miu, curR, curC, curX, rowsum,
                                        sR, sC, xE);
    k_rows<<<NN, 256, 0, stream>>>(curR, sR, curC, sC, curX, xE, rowsum,
                                   KU_weights, kToUconf, known, kToU, lmbda, A, b);
}